// Round 7
// baseline (850.493 us; speedup 1.0000x reference)
//
#include <hip/hip_runtime.h>

#define RCUT 3.5f
#define TTAB 2048
typedef unsigned long long u64;

static __device__ __forceinline__ float sigmoidf_(float x) { return 1.0f / (1.0f + expf(-x)); }
static __device__ __forceinline__ float siluf(float x) { return x / (1.0f + expf(-x)); }
// nan_to_num: 0 for NaN/Inf (bit-pattern test, fast-math immune)
static __device__ __forceinline__ float san(float x) {
    return ((__float_as_uint(x) & 0x7F800000u) != 0x7F800000u) ? x : 0.f;
}
static __device__ __forceinline__ unsigned short bf16rn(float f) {
    unsigned u = __float_as_uint(f);
    u = u + 0x7FFFu + ((u >> 16) & 1u);
    return (unsigned short)(u >> 16);
}
static __device__ __forceinline__ unsigned bfpack2(float a, float b) {
    return (unsigned)bf16rn(a) | ((unsigned)bf16rn(b) << 16);
}
static __device__ __forceinline__ float blo(unsigned u) { return __uint_as_float(u << 16); }
static __device__ __forceinline__ float bhi(unsigned u) { return __uint_as_float(u & 0xFFFF0000u); }
static __device__ __forceinline__ float bus(unsigned short s) {
    return __uint_as_float(((unsigned)s) << 16);
}

// ---------------- radial table: block per entry, thread per hidden unit ----------------------
__global__ __launch_bounds__(256) void k_table(const float* means, const float* betas,
                        const float* rad_w1, const float* rad_b1,
                        const float* rad_w2, const float* rad_b2,
                        const float* ne_dw, const float* ne_db,
                        float* tab) {
    __shared__ float red[3][4];
    int i = blockIdx.x;
    int h = threadIdx.x;
    int lane = h & 63, wv = h >> 6;
    float d  = (float)i * (RCUT / (float)(TTAB - 1));
    float dc = fmaxf(d, 1e-6f);
    float C  = (dc < RCUT) ? 0.5f * (cosf(dc * (3.14159265358979f / RCUT)) + 1.0f) : 0.0f;
    float ex = expf(-(5.0f / RCUT) * dc);
    float rbf[8];
#pragma unroll
    for (int nn = 0; nn < 8; ++nn) {
        float b = fmaxf(betas[nn], 1e-6f);
        float t = ex - means[nn];
        rbf[nn] = C * expf(-b * t * t);
    }
    float con[3];
#pragma unroll
    for (int l = 0; l < 3; ++l) {
        float cc = rad_b1[l * 256 + h];
#pragma unroll
        for (int nn = 0; nn < 8; ++nn) cc += rbf[nn] * rad_w1[(l * 8 + nn) * 256 + h];
        con[l] = siluf(cc) * rad_w2[l * 256 + h];
    }
#pragma unroll
    for (int m = 1; m < 64; m <<= 1) {
        con[0] += __shfl_xor(con[0], m, 64);
        con[1] += __shfl_xor(con[1], m, 64);
        con[2] += __shfl_xor(con[2], m, 64);
    }
    if (lane == 0) { red[0][wv] = con[0]; red[1][wv] = con[1]; red[2][wv] = con[2]; }
    __syncthreads();
    if (h < 3)
        tab[i * 40 + h] = rad_b2[h] + red[h][0] + red[h][1] + red[h][2] + red[h][3];
    else if (h == 3)
        tab[i * 40 + 3] = 0.f;
    else if (h < 36) {
        int c = h - 4;
        float wvv = ne_db[c];
#pragma unroll
        for (int nn = 0; nn < 8; ++nn) wvv += rbf[nn] * ne_dw[nn * 32 + c];
        tab[i * 40 + h] = wvv * C;   // W includes cutoff_fn(d)
    } else if (h < 40)
        tab[i * 40 + h] = 0.f;
}

// ---------------- count degrees ---------------------------------------------------------------
__global__ void k_count(const int* ei, int* cnt_dst, int* cnt_src, int E) {
    int e = blockIdx.x * blockDim.x + threadIdx.x;
    if (e >= E) return;
    atomicAdd(cnt_dst + ei[E + e], 1);
    atomicAdd(cnt_src + ei[e], 1);
}

// ---------------- dual exclusive scan (2 blocks, wave-scan based) ----------------------------
__global__ void k_scan2(const int* cntA, int* rowA, int* curA,
                        const int* cntB, int* rowB, int* curB, int n) {
    __shared__ int wtot[16];
    __shared__ int carry_s;
    const int* cnt = blockIdx.x ? cntB : cntA;
    int* rowptr    = blockIdx.x ? rowB : rowA;
    int* cursor    = blockIdx.x ? curB : curA;
    int tid = threadIdx.x, lane = tid & 63, wv = tid >> 6;
    if (tid == 0) carry_s = 0;
    __syncthreads();
    int nch = (n + 1023) >> 10;
    for (int ch = 0; ch < nch; ++ch) {
        int idx = (ch << 10) + tid;
        int val = (idx < n) ? cnt[idx] : 0;
        int v = val;
#pragma unroll
        for (int m = 1; m < 64; m <<= 1) {
            int t = __shfl_up(v, m, 64);
            if (lane >= m) v += t;
        }
        if (lane == 63) wtot[wv] = v;
        __syncthreads();
        int wbase = 0;
        for (int j = 0; j < wv; ++j) wbase += wtot[j];
        int base = carry_s;
        int incl = v + wbase;
        int excl = incl - val;
        if (idx < n) { rowptr[idx] = base + excl; cursor[idx] = base + excl; }
        __syncthreads();
        if (tid == 1023) carry_s = base + incl;
        __syncthreads();
    }
    if (tid == 0) rowptr[n] = carry_s;
}

// ---------------- fused edge-compute + scatter to dst-sorted bf16 records --------------------
// record (6 uints, 24B): u0=(ae0|ae1x) u1=(ae1y|ae1z) u2=(q00|q01) u3=(q02|q11) u4=(q12|q22) u5=0
// col_dst: srcn per slot. rec_src: {u (table coord, clamped), z[dst]}
__global__ void k_edge_fill(const float* pos, const float* alpha,
                            const int* ei, const float* tab, const int* z,
                            int* cur_dst, int* cur_src,
                            unsigned* rec_dst, int* col_dst, int2* rec_src, int E) {
    int e = blockIdx.x * blockDim.x + threadIdx.x;
    if (e >= E) return;
    int sn = ei[e], dn = ei[E + e];
    float rx = pos[dn * 3]     - pos[sn * 3];
    float ry = pos[dn * 3 + 1] - pos[sn * 3 + 1];
    float rz = pos[dn * 3 + 2] - pos[sn * 3 + 2];
    float d = sqrtf(rx * rx + ry * ry + rz * rz + 1e-12f);
    float inv = 1.0f / d;
    rx *= inv; ry *= inv; rz *= inv;
    float u = fminf(d, RCUT) * ((float)(TTAB - 1) / RCUT);
    int i0 = (int)u; if (i0 > TTAB - 2) i0 = TTAB - 2;
    float f = u - (float)i0;
    const float* t0 = tab + i0 * 40;
    float c0 = t0[0] + f * (t0[40] - t0[0]);
    float c1 = t0[1] + f * (t0[41] - t0[1]);
    float c2 = t0[2] + f * (t0[42] - t0[2]);
    float al = alpha[e];
    float ae0 = san(al * c0);
    float k1 = 1.73205081f * al * c1;      // sqrt(3)*alpha*coeff1
    float k2 = al * c2;
    float e20 = san(5.47722558f * rx * ry * k2);                             // sqrt(30) xy
    float e21 = san(5.47722558f * ry * rz * k2);
    float e22 = san(1.58113883f * (2.f * rz * rz - rx * rx - ry * ry) * k2); // sqrt(2.5)
    float e23 = san(5.47722558f * rx * rz * k2);
    float e24 = san(2.73861279f * (rx * rx - ry * ry) * k2);                 // sqrt(7.5)
    const float S2 = 0.70710678f, S6 = 0.40824829f;
    float q00 = -S6 * e22 + S2 * e24;
    float q01 = S2 * e20;
    float q02 = S2 * e23;
    float q11 = -S6 * e22 - S2 * e24;
    float q12 = S2 * e21;
    float q22 = 2.f * S6 * e22;
    int p = atomicAdd(cur_dst + dn, 1);
    unsigned* rp = rec_dst + (size_t)p * 6;
    rp[0] = bfpack2(ae0, san(k1 * rx));
    rp[1] = bfpack2(san(k1 * ry), san(k1 * rz));
    rp[2] = bfpack2(q00, q01);
    rp[3] = bfpack2(q02, q11);
    rp[4] = bfpack2(q12, q22);
    rp[5] = 0u;
    col_dst[p] = sn;
    int p2 = atomicAdd(cur_src + sn, 1);
    float uc = fminf(u, (float)(TTAB - 1) - 1e-3f);
    rec_src[p2] = make_int2(__float_as_int(uc), z[dn]);
}

// ---------------- aggr (src-sorted records) + initial node embed + bf16 mirrors --------------
__global__ __launch_bounds__(256) void k_aggr(const int* row_src, const int2* recs,
        const int* z, const float* tab, const float* ne_emb, const float* atom_emb,
        const float* ne_cw, const float* ne_cb,
        float* sbuf, float* vbuf, unsigned short* s16, unsigned short* v16, int N) {
    __shared__ float part[4][64];
    __shared__ float cat[4][64];
    int wv = threadIdx.x >> 6, lane = threadIdx.x & 63;
    int n = blockIdx.x * 4 + wv;
    bool act = n < N;
    int g = lane >> 5, li = lane & 31;
    float acc = 0.f;
    if (act) {
        int r0 = row_src[n], r1 = row_src[n + 1];
        int half = (r1 - r0) >> 1;
        int kb = g ? (r0 + half) : r0;
        int ke = g ? r1 : (r0 + half);
        int k = kb;
        for (; k + 2 <= ke; k += 2) {
            int2 rA = recs[k], rB = recs[k + 1];
            float uA = __int_as_float(rA.x), uB = __int_as_float(rB.x);
            int iA = (int)uA, iB = (int)uB;
            float fA = uA - (float)iA, fB = uB - (float)iB;
            float wA0 = tab[iA * 40 + 4 + li], wA1 = tab[iA * 40 + 44 + li];
            float wB0 = tab[iB * 40 + 4 + li], wB1 = tab[iB * 40 + 44 + li];
            float eA = ne_emb[rA.y * 32 + li], eB = ne_emb[rB.y * 32 + li];
            acc += (wA0 + fA * (wA1 - wA0)) * eA + (wB0 + fB * (wB1 - wB0)) * eB;
        }
        for (; k < ke; ++k) {
            int2 r = recs[k];
            float u = __int_as_float(r.x);
            int i0 = (int)u; float f = u - (float)i0;
            float w0 = tab[i0 * 40 + 4 + li], w1 = tab[i0 * 40 + 44 + li];
            acc += (w0 + f * (w1 - w0)) * ne_emb[r.y * 32 + li];
        }
    }
    part[wv][lane] = acc;
    __syncthreads();
    if (act && lane < 32) {
        cat[wv][lane] = atom_emb[z[n] * 32 + lane];
        cat[wv][32 + lane] = part[wv][lane] + part[wv][32 + lane];
    }
    __syncthreads();
    if (act && lane < 32) {
        float so = ne_cb[lane];
        for (int j = 0; j < 64; ++j) so += cat[wv][j] * ne_cw[j * 32 + lane];
        sbuf[n * 32 + lane] = so;
        s16[n * 32 + lane] = bf16rn(so);
    }
    if (act && lane < 48) { vbuf[n * 48 + lane] = 0.f; v16[n * 48 + lane] = 0; }
}

// ---------------- fused layer: moments (bf16 gathers, nt records) + node update --------------
// LDS per wave: M[352] moments | S[32] V[48] P[48] node scratch
__global__ __launch_bounds__(256) void k_layer(const int* row_dst, const unsigned* recs,
        const int* col, const unsigned short* s16, const unsigned short* v16,
        const float* sOld, const float* vOld,
        const float* w00, const float* w110, const float* w01,
        const float* w10, const float* w12,
        const float* self_ws, const float* self_wv,
        const float* pre_ws, const float* pre_wv,
        const float* post_ws, const float* post_wv,
        const float* ln_g, const float* ln_b,
        const float* g_w1, const float* g_b1,
        const float* g_w2, const float* g_b2,
        float* sNew, float* vNew, unsigned short* s16New, unsigned short* v16New,
        float* out, int N) {
    __shared__ float M[4][352];
    __shared__ float S[4][32], V[4][48], P[4][48];
    int wv = threadIdx.x >> 6, lane = threadIdx.x & 63;
    int n = blockIdx.x * 4 + wv;
    bool act = n < N;
    int c = lane >> 4, o = lane & 15;

    if (act && lane < 32) S[wv][lane] = sOld[n * 32 + lane];
    if (act && lane < 48) V[wv][lane] = vOld[n * 48 + lane];

    float a0 = 0.f, a1x = 0.f, a1y = 0.f, a1z = 0.f;
    float adv = 0.f, a2x = 0.f, a2y = 0.f, a2z = 0.f, a3x = 0.f, a3y = 0.f, a3z = 0.f;
    int r0 = 0, r1 = 0;
    if (act) { r0 = row_dst[n]; r1 = row_dst[n + 1]; }
    int s0 = 0, s1i = 0, s2i = 0, s3i = 0;
    if (r0 + 4 <= r1) {
        s0 = __builtin_nontemporal_load(col + r0);
        s1i = __builtin_nontemporal_load(col + r0 + 1);
        s2i = __builtin_nontemporal_load(col + r0 + 2);
        s3i = __builtin_nontemporal_load(col + r0 + 3);
    }
    int k = r0;
    for (; k + 4 <= r1; k += 4) {
        int c0 = s0, c1 = s1i, c2 = s2i, c3 = s3i;
        if (k + 8 <= r1) {
            s0 = __builtin_nontemporal_load(col + k + 4);
            s1i = __builtin_nontemporal_load(col + k + 5);
            s2i = __builtin_nontemporal_load(col + k + 6);
            s3i = __builtin_nontemporal_load(col + k + 7);
        }
        const unsigned* rb = recs + (size_t)k * 6;
        if (lane < 32) {
            u64 p0 = __builtin_nontemporal_load((const u64*)rb);
            u64 p1 = __builtin_nontemporal_load((const u64*)(rb + 6));
            u64 p2 = __builtin_nontemporal_load((const u64*)(rb + 12));
            u64 p3 = __builtin_nontemporal_load((const u64*)(rb + 18));
            float x0 = bus(s16[c0 * 32 + lane]);
            float x1 = bus(s16[c1 * 32 + lane]);
            float x2 = bus(s16[c2 * 32 + lane]);
            float x3 = bus(s16[c3 * 32 + lane]);
            unsigned u00 = (unsigned)p0, u01 = (unsigned)(p0 >> 32);
            unsigned u10 = (unsigned)p1, u11 = (unsigned)(p1 >> 32);
            unsigned u20 = (unsigned)p2, u21 = (unsigned)(p2 >> 32);
            unsigned u30 = (unsigned)p3, u31 = (unsigned)(p3 >> 32);
            a0  += x0 * blo(u00) + x1 * blo(u10) + x2 * blo(u20) + x3 * blo(u30);
            a1x += x0 * bhi(u00) + x1 * bhi(u10) + x2 * bhi(u20) + x3 * bhi(u30);
            a1y += x0 * blo(u01) + x1 * blo(u11) + x2 * blo(u21) + x3 * blo(u31);
            a1z += x0 * bhi(u01) + x1 * bhi(u11) + x2 * bhi(u21) + x3 * bhi(u31);
        } else {
            int g = (lane >> 4) & 1, m = lane & 15;
            const unsigned* rbA = rb + g * 12;      // edges k+2g, k+2g+1
            u64 pa01 = __builtin_nontemporal_load((const u64*)rbA);
            u64 pa23 = __builtin_nontemporal_load((const u64*)(rbA + 2));
            unsigned ua4 = __builtin_nontemporal_load(rbA + 4);
            u64 pb01 = __builtin_nontemporal_load((const u64*)(rbA + 6));
            u64 pb23 = __builtin_nontemporal_load((const u64*)(rbA + 8));
            unsigned ub4 = __builtin_nontemporal_load(rbA + 10);
            int sA = g ? c2 : c0, sB = g ? c3 : c1;
            const unsigned short* vpA = v16 + (size_t)sA * 48;
            const unsigned short* vpB = v16 + (size_t)sB * 48;
            float vxA = bus(vpA[m]), vyA = bus(vpA[16 + m]), vzA = bus(vpA[32 + m]);
            float vxB = bus(vpB[m]), vyB = bus(vpB[16 + m]), vzB = bus(vpB[32 + m]);
            unsigned a_u0 = (unsigned)pa01, a_u1 = (unsigned)(pa01 >> 32);
            unsigned a_u2 = (unsigned)pa23, a_u3 = (unsigned)(pa23 >> 32);
            unsigned b_u0 = (unsigned)pb01, b_u1 = (unsigned)(pb01 >> 32);
            unsigned b_u2 = (unsigned)pb23, b_u3 = (unsigned)(pb23 >> 32);
            float aA0 = blo(a_u0), aAx = bhi(a_u0), aAy = blo(a_u1), aAz = bhi(a_u1);
            float qA00 = blo(a_u2), qA01 = bhi(a_u2), qA02 = blo(a_u3), qA11 = bhi(a_u3);
            float qA12 = blo(ua4), qA22 = bhi(ua4);
            float aB0 = blo(b_u0), aBx = bhi(b_u0), aBy = blo(b_u1), aBz = bhi(b_u1);
            float qB00 = blo(b_u2), qB01 = bhi(b_u2), qB02 = blo(b_u3), qB11 = bhi(b_u3);
            float qB12 = blo(ub4), qB22 = bhi(ub4);
            adv += vxA * aAx + vyA * aAy + vzA * aAz + vxB * aBx + vyB * aBy + vzB * aBz;
            a2x += vxA * aA0 + vxB * aB0;
            a2y += vyA * aA0 + vyB * aB0;
            a2z += vzA * aA0 + vzB * aB0;
            a3x += qA00 * vxA + qA01 * vyA + qA02 * vzA + qB00 * vxB + qB01 * vyB + qB02 * vzB;
            a3y += qA01 * vxA + qA11 * vyA + qA12 * vzA + qB01 * vxB + qB11 * vyB + qB12 * vzB;
            a3z += qA02 * vxA + qA12 * vyA + qA22 * vzA + qB02 * vxB + qB12 * vyB + qB22 * vzB;
        }
    }
    for (; k < r1; ++k) {                      // tail
        const unsigned* rb = recs + (size_t)k * 6;
        int sn = __builtin_nontemporal_load(col + k);
        if (lane < 32) {
            u64 p0 = __builtin_nontemporal_load((const u64*)rb);
            unsigned u0 = (unsigned)p0, u1 = (unsigned)(p0 >> 32);
            float ssi = bus(s16[sn * 32 + lane]);
            a0 += ssi * blo(u0); a1x += ssi * bhi(u0);
            a1y += ssi * blo(u1); a1z += ssi * bhi(u1);
        } else if (lane < 48) {
            u64 p01 = __builtin_nontemporal_load((const u64*)rb);
            u64 p23 = __builtin_nontemporal_load((const u64*)(rb + 2));
            unsigned u4 = __builtin_nontemporal_load(rb + 4);
            int m = lane - 32;
            const unsigned short* vp = v16 + (size_t)sn * 48;
            float vx = bus(vp[m]), vy = bus(vp[16 + m]), vz = bus(vp[32 + m]);
            unsigned u0 = (unsigned)p01, u1 = (unsigned)(p01 >> 32);
            unsigned u2 = (unsigned)p23, u3 = (unsigned)(p23 >> 32);
            float ae0 = blo(u0), aex = bhi(u0), aey = blo(u1), aez = bhi(u1);
            float q00 = blo(u2), q01 = bhi(u2), q02 = blo(u3), q11 = bhi(u3);
            float q12 = blo(u4), q22 = bhi(u4);
            adv += vx * aex + vy * aey + vz * aez;
            a2x += vx * ae0; a2y += vy * ae0; a2z += vz * ae0;
            a3x += q00 * vx + q01 * vy + q02 * vz;
            a3y += q01 * vx + q11 * vy + q12 * vz;
            a3z += q02 * vx + q12 * vy + q22 * vz;
        }
    }
    if (lane < 32) {
        M[wv][lane] = a0; M[wv][32 + lane] = a1x;
        M[wv][64 + lane] = a1y; M[wv][96 + lane] = a1z;
    } else {
        int g = (lane >> 4) & 1, m = lane & 15;
        int base = 128 + g * 112;
        M[wv][base + m] = adv;
        M[wv][base + 16 + m] = a2x; M[wv][base + 32 + m] = a2y; M[wv][base + 48 + m] = a2z;
        M[wv][base + 64 + m] = a3x; M[wv][base + 80 + m] = a3y; M[wv][base + 96 + m] = a3z;
    }
    __syncthreads();
    // ---- node update (k_node logic, moments read straight from M) ----
    float s1 = 0.f, v1 = 0.f;
    if (act && lane < 32) {
        for (int i = 0; i < 32; ++i) s1 += M[wv][i] * w00[i * 32 + lane];
        for (int v = 0; v < 16; ++v)
            s1 += (M[wv][128 + v] + M[wv][240 + v]) * w110[v * 32 + lane];
        for (int i = 0; i < 32; ++i) s1 += S[wv][i] * self_ws[i * 32 + lane];
    }
    if (act && lane < 48) {
        for (int i = 0; i < 32; ++i) v1 += M[wv][32 + c * 32 + i] * w01[i * 16 + o];
        for (int v = 0; v < 16; ++v)
            v1 += (M[wv][144 + c * 16 + v] + M[wv][256 + c * 16 + v]) * w10[v * 16 + o];
        for (int v = 0; v < 16; ++v)
            v1 += (M[wv][192 + c * 16 + v] + M[wv][304 + c * 16 + v]) * w12[v * 16 + o];
        for (int v = 0; v < 16; ++v) v1 += V[wv][c * 16 + v] * self_wv[v * 16 + o];
    }
    __syncthreads();
    if (lane < 32) S[wv][lane] = s1;
    if (lane < 48) V[wv][lane] = v1;
    __syncthreads();
    float ps = 0.f, pv = 0.f;
    if (act && lane < 48) {
        for (int i = 0; i < 32; ++i) ps += S[wv][i] * pre_ws[i * 48 + lane];
        for (int v = 0; v < 16; ++v) pv += V[wv][c * 16 + v] * pre_wv[v * 16 + o];
    }
    if (lane < 48) P[wv][lane] = ps;
    __syncthreads();
    float g  = sigmoidf_(P[wv][32 + o]);
    float sc = (lane < 32) ? siluf(ps) : 0.f;
    float v2 = pv * g;
    __syncthreads();
    if (lane < 32) S[wv][lane] = sc;
    if (lane < 48) V[wv][lane] = v2;
    __syncthreads();
    float s2 = 0.f, v3 = 0.f;
    if (act && lane < 32) { for (int i = 0; i < 32; ++i) s2 += S[wv][i] * post_ws[i * 32 + lane]; }
    if (act && lane < 48) { for (int v = 0; v < 16; ++v) v3 += V[wv][c * 16 + v] * post_wv[v * 16 + o]; }
    __syncthreads();
    if (lane < 32) S[wv][lane] = s2;
    if (lane < 48) V[wv][lane] = v3;
    __syncthreads();
    float sln = 0.f;
    if (act && lane < 32) {
        float mu = 0.f;
        for (int i = 0; i < 32; ++i) mu += S[wv][i];
        mu *= (1.0f / 32.0f);
        float var = 0.f;
        for (int i = 0; i < 32; ++i) { float t = S[wv][i] - mu; var += t * t; }
        var *= (1.0f / 32.0f);
        sln = (s2 - mu) * rsqrtf(var + 1e-5f) * ln_g[lane] + ln_b[lane];
    }
    if (lane < 16) {
        float vx = V[wv][lane], vy = V[wv][16 + lane], vz = V[wv][32 + lane];
        P[wv][lane] = sqrtf(vx * vx + vy * vy + vz * vz + 1e-12f);
    }
    __syncthreads();
    if (lane < 16) {
        float x = g_b1[lane];
        for (int m = 0; m < 16; ++m) x += P[wv][m] * g_w1[m * 16 + lane];
        P[wv][16 + lane] = siluf(x);
    }
    __syncthreads();
    float sfin = 0.f;
    if (act && lane < 32) {
        float dl = g_b2[lane];
        for (int oo = 0; oo < 16; ++oo) dl += P[wv][16 + oo] * g_w2[oo * 32 + lane];
        sfin = sln + dl;
    }
    if (out) {
        if (act && lane < 32) out[(size_t)n * 80 + lane] = sfin;
        if (act && lane < 48) out[(size_t)n * 80 + 32 + o * 3 + c] = v3;
    } else {
        if (act && lane < 32) {
            sNew[n * 32 + lane] = sfin;
            s16New[n * 32 + lane] = bf16rn(sfin);
        }
        if (act && lane < 48) {
            vNew[n * 48 + lane] = v3;
            v16New[n * 48 + lane] = bf16rn(v3);
        }
    }
}

extern "C" void kernel_launch(void* const* d_in, const int* in_sizes, int n_in,
                              void* d_out, int out_size, void* d_ws, size_t ws_size,
                              hipStream_t stream) {
    auto F = [&](int i) { return (const float*)d_in[i]; };
    const int* z  = (const int*)d_in[31];
    const int* ei = (const int*)d_in[32];
    int N = in_sizes[0] / 3;
    int E = in_sizes[1];

    char* w = (char*)d_ws;
    size_t off = 0;
    auto take = [&](size_t bytes) { size_t cur = off; off += (bytes + 255) & ~(size_t)255; return cur; };
    unsigned* rec_dst = (unsigned*)(w + take((size_t)E * 24));
    int*   col_dst = (int*)(w + take((size_t)E * 4));
    int2*  rec_src = (int2*)(w + take((size_t)E * 8));
    float* tab     = (float*)(w + take((size_t)TTAB * 40 * 4));
    int* cnt_dst   = (int*)(w + take((size_t)2 * N * 4));
    int* cnt_src   = cnt_dst + N;
    int* row_dst   = (int*)(w + take((size_t)(N + 1) * 4));
    int* row_src   = (int*)(w + take((size_t)(N + 1) * 4));
    int* cur_dst   = (int*)(w + take((size_t)N * 4));
    int* cur_src   = (int*)(w + take((size_t)N * 4));
    float* sA      = (float*)(w + take((size_t)N * 32 * 4));
    float* vA      = (float*)(w + take((size_t)N * 48 * 4));
    float* sB      = (float*)(w + take((size_t)N * 32 * 4));
    float* vB      = (float*)(w + take((size_t)N * 48 * 4));
    unsigned short* s16A = (unsigned short*)(w + take((size_t)N * 32 * 2));
    unsigned short* v16A = (unsigned short*)(w + take((size_t)N * 48 * 2));
    unsigned short* s16B = (unsigned short*)(w + take((size_t)N * 32 * 2));
    unsigned short* v16B = (unsigned short*)(w + take((size_t)N * 48 * 2));

    hipMemsetAsync(cnt_dst, 0, (size_t)2 * N * 4, stream);

    k_table<<<TTAB, 256, 0, stream>>>(F(8), F(9), F(10), F(11),
                                      F(12), F(13), F(4), F(5), tab);
    k_count<<<(E + 255) / 256, 256, 0, stream>>>(ei, cnt_dst, cnt_src, E);
    k_scan2<<<2, 1024, 0, stream>>>(cnt_dst, row_dst, cur_dst,
                                    cnt_src, row_src, cur_src, N);
    k_edge_fill<<<(E + 255) / 256, 256, 0, stream>>>(F(0), F(1), ei, tab, z,
                                                     cur_dst, cur_src,
                                                     rec_dst, col_dst, rec_src, E);

    int nb = (N + 3) / 4;
    k_aggr<<<nb, 256, 0, stream>>>(row_src, rec_src, z, tab, F(3), F(2),
                                   F(6), F(7), sA, vA, s16A, v16A, N);

    float* sIn = sA; float* vIn = vA; unsigned short* s16In = s16A; unsigned short* v16In = v16A;
    float* sOut = sB; float* vOut = vB; unsigned short* s16Out = s16B; unsigned short* v16Out = v16B;
    for (int li = 0; li < 4; ++li) {
        float* outp = (li == 3) ? (float*)d_out : nullptr;
        k_layer<<<nb, 256, 0, stream>>>(row_dst, rec_dst, col_dst, s16In, v16In, sIn, vIn,
                                        F(14) + li * 32 * 32, F(15) + li * 16 * 32,
                                        F(16) + li * 32 * 16, F(17) + li * 16 * 16,
                                        F(18) + li * 16 * 16,
                                        F(19) + li * 32 * 32, F(20) + li * 16 * 16,
                                        F(21) + li * 32 * 48, F(22) + li * 16 * 16,
                                        F(23) + li * 32 * 32, F(24) + li * 16 * 16,
                                        F(25) + li * 32, F(26) + li * 32,
                                        F(27) + li * 16 * 16, F(28) + li * 16,
                                        F(29) + li * 16 * 32, F(30) + li * 32,
                                        sOut, vOut, s16Out, v16Out, outp, N);
        float* ts = sIn; sIn = sOut; sOut = ts;
        float* tv = vIn; vIn = vOut; vOut = tv;
        unsigned short* t16 = s16In; s16In = s16Out; s16Out = t16;
        unsigned short* tv16 = v16In; v16In = v16Out; v16Out = tv16;
    }
}

// Round 9
// 795.280 us; speedup vs baseline: 1.0694x; 1.0694x over previous
//
#include <hip/hip_runtime.h>

#define RCUT 3.5f
#define TTAB 2048

static __device__ __forceinline__ float sigmoidf_(float x) { return 1.0f / (1.0f + expf(-x)); }
static __device__ __forceinline__ float siluf(float x) { return x / (1.0f + expf(-x)); }
// nan_to_num: 0 for NaN/Inf (bit-pattern test, fast-math immune)
static __device__ __forceinline__ float san(float x) {
    return ((__float_as_uint(x) & 0x7F800000u) != 0x7F800000u) ? x : 0.f;
}
static __device__ __forceinline__ unsigned short bf16rn(float f) {
    unsigned u = __float_as_uint(f);
    u = u + 0x7FFFu + ((u >> 16) & 1u);
    return (unsigned short)(u >> 16);
}
static __device__ __forceinline__ float bus(unsigned short s) {
    return __uint_as_float(((unsigned)s) << 16);
}

// ---------------- radial table: block per entry, thread per hidden unit ----------------------
__global__ __launch_bounds__(256) void k_table(const float* means, const float* betas,
                        const float* rad_w1, const float* rad_b1,
                        const float* rad_w2, const float* rad_b2,
                        const float* ne_dw, const float* ne_db,
                        float* tab) {
    __shared__ float red[3][4];
    int i = blockIdx.x;
    int h = threadIdx.x;
    int lane = h & 63, wv = h >> 6;
    float d  = (float)i * (RCUT / (float)(TTAB - 1));
    float dc = fmaxf(d, 1e-6f);
    float C  = (dc < RCUT) ? 0.5f * (cosf(dc * (3.14159265358979f / RCUT)) + 1.0f) : 0.0f;
    float ex = expf(-(5.0f / RCUT) * dc);
    float rbf[8];
#pragma unroll
    for (int nn = 0; nn < 8; ++nn) {
        float b = fmaxf(betas[nn], 1e-6f);
        float t = ex - means[nn];
        rbf[nn] = C * expf(-b * t * t);
    }
    float con[3];
#pragma unroll
    for (int l = 0; l < 3; ++l) {
        float cc = rad_b1[l * 256 + h];
#pragma unroll
        for (int nn = 0; nn < 8; ++nn) cc += rbf[nn] * rad_w1[(l * 8 + nn) * 256 + h];
        con[l] = siluf(cc) * rad_w2[l * 256 + h];
    }
#pragma unroll
    for (int m = 1; m < 64; m <<= 1) {
        con[0] += __shfl_xor(con[0], m, 64);
        con[1] += __shfl_xor(con[1], m, 64);
        con[2] += __shfl_xor(con[2], m, 64);
    }
    if (lane == 0) { red[0][wv] = con[0]; red[1][wv] = con[1]; red[2][wv] = con[2]; }
    __syncthreads();
    if (h < 3)
        tab[i * 40 + h] = rad_b2[h] + red[h][0] + red[h][1] + red[h][2] + red[h][3];
    else if (h == 3)
        tab[i * 40 + 3] = 0.f;
    else if (h < 36) {
        int c = h - 4;
        float wvv = ne_db[c];
#pragma unroll
        for (int nn = 0; nn < 8; ++nn) wvv += rbf[nn] * ne_dw[nn * 32 + c];
        tab[i * 40 + h] = wvv * C;   // W includes cutoff_fn(d)
    } else if (h < 40)
        tab[i * 40 + h] = 0.f;
}

// ---------------- count degrees ---------------------------------------------------------------
__global__ void k_count(const int* ei, int* cnt_dst, int* cnt_src, int E) {
    int e = blockIdx.x * blockDim.x + threadIdx.x;
    if (e >= E) return;
    atomicAdd(cnt_dst + ei[E + e], 1);
    atomicAdd(cnt_src + ei[e], 1);
}

// ---------------- dual exclusive scan (2 blocks, wave-scan based) ----------------------------
__global__ void k_scan2(const int* cntA, int* rowA, int* curA,
                        const int* cntB, int* rowB, int* curB, int n) {
    __shared__ int wtot[16];
    __shared__ int carry_s;
    const int* cnt = blockIdx.x ? cntB : cntA;
    int* rowptr    = blockIdx.x ? rowB : rowA;
    int* cursor    = blockIdx.x ? curB : curA;
    int tid = threadIdx.x, lane = tid & 63, wv = tid >> 6;
    if (tid == 0) carry_s = 0;
    __syncthreads();
    int nch = (n + 1023) >> 10;
    for (int ch = 0; ch < nch; ++ch) {
        int idx = (ch << 10) + tid;
        int val = (idx < n) ? cnt[idx] : 0;
        int v = val;
#pragma unroll
        for (int m = 1; m < 64; m <<= 1) {
            int t = __shfl_up(v, m, 64);
            if (lane >= m) v += t;
        }
        if (lane == 63) wtot[wv] = v;
        __syncthreads();
        int wbase = 0;
        for (int j = 0; j < wv; ++j) wbase += wtot[j];
        int base = carry_s;
        int incl = v + wbase;
        int excl = incl - val;
        if (idx < n) { rowptr[idx] = base + excl; cursor[idx] = base + excl; }
        __syncthreads();
        if (tid == 1023) carry_s = base + incl;
        __syncthreads();
    }
    if (tid == 0) rowptr[n] = carry_s;
}

// ---------------- fused edge-compute + scatter to dst-sorted f32 SoA records -----------------
// recA: float4 [ae0, ae1x, ae1y, ae1z]; recQ4: float4 [q00,q01,q02,q11]; recQ2: float2 [q12,q22]
// col: srcn per slot. rec_src: {u (table coord, clamped), z[dst]}
__global__ void k_edge_fill(const float* pos, const float* alpha,
                            const int* ei, const float* tab, const int* z,
                            int* cur_dst, int* cur_src,
                            float4* recA, float4* recQ4, float2* recQ2, int* col_dst,
                            int2* rec_src, int E) {
    int e = blockIdx.x * blockDim.x + threadIdx.x;
    if (e >= E) return;
    int sn = ei[e], dn = ei[E + e];
    float rx = pos[dn * 3]     - pos[sn * 3];
    float ry = pos[dn * 3 + 1] - pos[sn * 3 + 1];
    float rz = pos[dn * 3 + 2] - pos[sn * 3 + 2];
    float d = sqrtf(rx * rx + ry * ry + rz * rz + 1e-12f);
    float inv = 1.0f / d;
    rx *= inv; ry *= inv; rz *= inv;
    float u = fminf(d, RCUT) * ((float)(TTAB - 1) / RCUT);
    int i0 = (int)u; if (i0 > TTAB - 2) i0 = TTAB - 2;
    float f = u - (float)i0;
    const float* t0 = tab + i0 * 40;
    float c0 = t0[0] + f * (t0[40] - t0[0]);
    float c1 = t0[1] + f * (t0[41] - t0[1]);
    float c2 = t0[2] + f * (t0[42] - t0[2]);
    float al = alpha[e];
    float ae0 = san(al * c0);
    float k1 = 1.73205081f * al * c1;      // sqrt(3)*alpha*coeff1
    float k2 = al * c2;
    float e20 = san(5.47722558f * rx * ry * k2);                             // sqrt(30) xy
    float e21 = san(5.47722558f * ry * rz * k2);
    float e22 = san(1.58113883f * (2.f * rz * rz - rx * rx - ry * ry) * k2); // sqrt(2.5)
    float e23 = san(5.47722558f * rx * rz * k2);
    float e24 = san(2.73861279f * (rx * rx - ry * ry) * k2);                 // sqrt(7.5)
    const float S2 = 0.70710678f, S6 = 0.40824829f;
    float q00 = -S6 * e22 + S2 * e24;
    float q01 = S2 * e20;
    float q02 = S2 * e23;
    float q11 = -S6 * e22 - S2 * e24;
    float q12 = S2 * e21;
    float q22 = 2.f * S6 * e22;
    int p = atomicAdd(cur_dst + dn, 1);
    recA[p]  = make_float4(ae0, san(k1 * rx), san(k1 * ry), san(k1 * rz));
    recQ4[p] = make_float4(q00, q01, q02, q11);
    recQ2[p] = make_float2(q12, q22);
    col_dst[p] = sn;
    int p2 = atomicAdd(cur_src + sn, 1);
    float uc = fminf(u, (float)(TTAB - 1) - 1e-3f);
    rec_src[p2] = make_int2(__float_as_int(uc), z[dn]);
}

// ---------------- aggr (src-sorted records) + initial node embed + bf16 mirrors --------------
__global__ __launch_bounds__(256) void k_aggr(const int* row_src, const int2* recs,
        const int* z, const float* tab, const float* ne_emb, const float* atom_emb,
        const float* ne_cw, const float* ne_cb,
        float* sbuf, float* vbuf, unsigned short* s16, unsigned short* v16, int N) {
    __shared__ float part[4][64];
    __shared__ float cat[4][64];
    int wv = threadIdx.x >> 6, lane = threadIdx.x & 63;
    int n = blockIdx.x * 4 + wv;
    bool act = n < N;
    int g = lane >> 5, li = lane & 31;
    float acc = 0.f;
    if (act) {
        int r0 = row_src[n], r1 = row_src[n + 1];
        int half = (r1 - r0) >> 1;
        int kb = g ? (r0 + half) : r0;
        int ke = g ? r1 : (r0 + half);
        int k = kb;
        for (; k + 2 <= ke; k += 2) {
            int2 rA = recs[k], rB = recs[k + 1];
            float uA = __int_as_float(rA.x), uB = __int_as_float(rB.x);
            int iA = (int)uA, iB = (int)uB;
            float fA = uA - (float)iA, fB = uB - (float)iB;
            float wA0 = tab[iA * 40 + 4 + li], wA1 = tab[iA * 40 + 44 + li];
            float wB0 = tab[iB * 40 + 4 + li], wB1 = tab[iB * 40 + 44 + li];
            float eA = ne_emb[rA.y * 32 + li], eB = ne_emb[rB.y * 32 + li];
            acc += (wA0 + fA * (wA1 - wA0)) * eA + (wB0 + fB * (wB1 - wB0)) * eB;
        }
        for (; k < ke; ++k) {
            int2 r = recs[k];
            float u = __int_as_float(r.x);
            int i0 = (int)u; float f = u - (float)i0;
            float w0 = tab[i0 * 40 + 4 + li], w1 = tab[i0 * 40 + 44 + li];
            acc += (w0 + f * (w1 - w0)) * ne_emb[r.y * 32 + li];
        }
    }
    part[wv][lane] = acc;
    __syncthreads();
    if (act && lane < 32) {
        cat[wv][lane] = atom_emb[z[n] * 32 + lane];
        cat[wv][32 + lane] = part[wv][lane] + part[wv][32 + lane];
    }
    __syncthreads();
    if (act && lane < 32) {
        float so = ne_cb[lane];
        for (int j = 0; j < 64; ++j) so += cat[wv][j] * ne_cw[j * 32 + lane];
        sbuf[n * 32 + lane] = so;
        s16[n * 32 + lane] = bf16rn(so);
    }
    if (act && lane < 48) { vbuf[n * 48 + lane] = 0.f; v16[n * 48 + lane] = 0; }
}

// ---------------- fused layer: f32 SoA records, bf16 gathers, node update --------------------
// LDS per wave: M[352] moments | S[32] V[48] P[48] node scratch
__global__ __launch_bounds__(256) void k_layer(const int* __restrict__ row_dst,
        const float4* __restrict__ recA, const float4* __restrict__ recQ4,
        const float2* __restrict__ recQ2, const int* __restrict__ col,
        const unsigned short* __restrict__ s16, const unsigned short* __restrict__ v16,
        const float* __restrict__ sOld, const float* __restrict__ vOld,
        const float* w00, const float* w110, const float* w01,
        const float* w10, const float* w12,
        const float* self_ws, const float* self_wv,
        const float* pre_ws, const float* pre_wv,
        const float* post_ws, const float* post_wv,
        const float* ln_g, const float* ln_b,
        const float* g_w1, const float* g_b1,
        const float* g_w2, const float* g_b2,
        float* sNew, float* vNew, unsigned short* s16New, unsigned short* v16New,
        float* out, int N) {
    __shared__ float M[4][352];
    __shared__ float S[4][32], V[4][48], P[4][48];
    int wv = threadIdx.x >> 6, lane = threadIdx.x & 63;
    int n = blockIdx.x * 4 + wv;
    bool act = n < N;
    int c = lane >> 4, o = lane & 15;

    if (act && lane < 32) S[wv][lane] = sOld[n * 32 + lane];
    if (act && lane < 48) V[wv][lane] = vOld[n * 48 + lane];

    float a0 = 0.f, a1x = 0.f, a1y = 0.f, a1z = 0.f;
    float adv = 0.f, a2x = 0.f, a2y = 0.f, a2z = 0.f, a3x = 0.f, a3y = 0.f, a3z = 0.f;
    int r0 = 0, r1 = 0;
    if (act) { r0 = row_dst[n]; r1 = row_dst[n + 1]; }
    int g = (lane >> 4) & 1, m = lane & 15;
    int s0 = 0, s1i = 0, s2i = 0, s3i = 0;
    if (r0 + 4 <= r1) {
        s0 = col[r0]; s1i = col[r0 + 1]; s2i = col[r0 + 2]; s3i = col[r0 + 3];
    }
    int k = r0;
    for (; k + 4 <= r1; k += 4) {
        int c0 = s0, c1 = s1i, c2 = s2i, c3 = s3i;
        if (k + 8 <= r1) {
            s0 = col[k + 4]; s1i = col[k + 5]; s2i = col[k + 6]; s3i = col[k + 7];
        }
        if (lane < 32) {
            float4 A0 = recA[k], A1 = recA[k + 1], A2 = recA[k + 2], A3 = recA[k + 3];
            float x0 = bus(s16[c0 * 32 + lane]);
            float x1 = bus(s16[c1 * 32 + lane]);
            float x2 = bus(s16[c2 * 32 + lane]);
            float x3 = bus(s16[c3 * 32 + lane]);
            a0  += x0 * A0.x + x1 * A1.x + x2 * A2.x + x3 * A3.x;
            a1x += x0 * A0.y + x1 * A1.y + x2 * A2.y + x3 * A3.y;
            a1y += x0 * A0.z + x1 * A1.z + x2 * A2.z + x3 * A3.z;
            a1z += x0 * A0.w + x1 * A1.w + x2 * A2.w + x3 * A3.w;
        } else {
            int ea = k + 2 * g, eb = ea + 1;
            float4 Aa = recA[ea],  Ab = recA[eb];
            float4 Qa = recQ4[ea], Qb = recQ4[eb];
            float2 Pa = recQ2[ea], Pb = recQ2[eb];
            int sA = g ? c2 : c0, sB = g ? c3 : c1;
            const unsigned short* vpA = v16 + (size_t)sA * 48;
            const unsigned short* vpB = v16 + (size_t)sB * 48;
            float vxA = bus(vpA[m]), vyA = bus(vpA[16 + m]), vzA = bus(vpA[32 + m]);
            float vxB = bus(vpB[m]), vyB = bus(vpB[16 + m]), vzB = bus(vpB[32 + m]);
            adv += vxA * Aa.y + vyA * Aa.z + vzA * Aa.w + vxB * Ab.y + vyB * Ab.z + vzB * Ab.w;
            a2x += vxA * Aa.x + vxB * Ab.x;
            a2y += vyA * Aa.x + vyB * Ab.x;
            a2z += vzA * Aa.x + vzB * Ab.x;
            a3x += Qa.x * vxA + Qa.y * vyA + Qa.z * vzA + Qb.x * vxB + Qb.y * vyB + Qb.z * vzB;
            a3y += Qa.y * vxA + Qa.w * vyA + Pa.x * vzA + Qb.y * vxB + Qb.w * vyB + Pb.x * vzB;
            a3z += Qa.z * vxA + Pa.x * vyA + Pa.y * vzA + Qb.z * vxB + Pb.x * vyB + Pb.y * vzB;
        }
    }
    for (; k < r1; ++k) {                      // tail
        int cc = col[k];
        float4 A = recA[k];
        if (lane < 32) {
            float ssi = bus(s16[cc * 32 + lane]);
            a0 += ssi * A.x; a1x += ssi * A.y; a1y += ssi * A.z; a1z += ssi * A.w;
        } else if (lane < 48) {
            float4 Q = recQ4[k];
            float2 Pq = recQ2[k];
            int mm = lane - 32;
            const unsigned short* vp = v16 + (size_t)cc * 48;
            float vx = bus(vp[mm]), vy = bus(vp[16 + mm]), vz = bus(vp[32 + mm]);
            adv += vx * A.y + vy * A.z + vz * A.w;
            a2x += vx * A.x; a2y += vy * A.x; a2z += vz * A.x;
            a3x += Q.x * vx + Q.y * vy + Q.z * vz;
            a3y += Q.y * vx + Q.w * vy + Pq.x * vz;
            a3z += Q.z * vx + Pq.x * vy + Pq.y * vz;
        }
    }
    if (lane < 32) {
        M[wv][lane] = a0; M[wv][32 + lane] = a1x;
        M[wv][64 + lane] = a1y; M[wv][96 + lane] = a1z;
    } else {
        int base = 128 + g * 112;
        M[wv][base + m] = adv;
        M[wv][base + 16 + m] = a2x; M[wv][base + 32 + m] = a2y; M[wv][base + 48 + m] = a2z;
        M[wv][base + 64 + m] = a3x; M[wv][base + 80 + m] = a3y; M[wv][base + 96 + m] = a3z;
    }
    __syncthreads();
    // ---- node update ----
    float s1 = 0.f, v1 = 0.f;
    if (act && lane < 32) {
        for (int i = 0; i < 32; ++i) s1 += M[wv][i] * w00[i * 32 + lane];
        for (int v = 0; v < 16; ++v)
            s1 += (M[wv][128 + v] + M[wv][240 + v]) * w110[v * 32 + lane];
        for (int i = 0; i < 32; ++i) s1 += S[wv][i] * self_ws[i * 32 + lane];
    }
    if (act && lane < 48) {
        for (int i = 0; i < 32; ++i) v1 += M[wv][32 + c * 32 + i] * w01[i * 16 + o];
        for (int v = 0; v < 16; ++v)
            v1 += (M[wv][144 + c * 16 + v] + M[wv][256 + c * 16 + v]) * w10[v * 16 + o];
        for (int v = 0; v < 16; ++v)
            v1 += (M[wv][192 + c * 16 + v] + M[wv][304 + c * 16 + v]) * w12[v * 16 + o];
        for (int v = 0; v < 16; ++v) v1 += V[wv][c * 16 + v] * self_wv[v * 16 + o];
    }
    __syncthreads();
    if (lane < 32) S[wv][lane] = s1;
    if (lane < 48) V[wv][lane] = v1;
    __syncthreads();
    float ps = 0.f, pv = 0.f;
    if (act && lane < 48) {
        for (int i = 0; i < 32; ++i) ps += S[wv][i] * pre_ws[i * 48 + lane];
        for (int v = 0; v < 16; ++v) pv += V[wv][c * 16 + v] * pre_wv[v * 16 + o];
    }
    if (lane < 48) P[wv][lane] = ps;
    __syncthreads();
    float gg = sigmoidf_(P[wv][32 + o]);
    float sc = (lane < 32) ? siluf(ps) : 0.f;
    float v2 = pv * gg;
    __syncthreads();
    if (lane < 32) S[wv][lane] = sc;
    if (lane < 48) V[wv][lane] = v2;
    __syncthreads();
    float s2 = 0.f, v3 = 0.f;
    if (act && lane < 32) { for (int i = 0; i < 32; ++i) s2 += S[wv][i] * post_ws[i * 32 + lane]; }
    if (act && lane < 48) { for (int v = 0; v < 16; ++v) v3 += V[wv][c * 16 + v] * post_wv[v * 16 + o]; }
    __syncthreads();
    if (lane < 32) S[wv][lane] = s2;
    if (lane < 48) V[wv][lane] = v3;
    __syncthreads();
    float sln = 0.f;
    if (act && lane < 32) {
        float mu = 0.f;
        for (int i = 0; i < 32; ++i) mu += S[wv][i];
        mu *= (1.0f / 32.0f);
        float var = 0.f;
        for (int i = 0; i < 32; ++i) { float t = S[wv][i] - mu; var += t * t; }
        var *= (1.0f / 32.0f);
        sln = (s2 - mu) * rsqrtf(var + 1e-5f) * ln_g[lane] + ln_b[lane];
    }
    if (lane < 16) {
        float vx = V[wv][lane], vy = V[wv][16 + lane], vz = V[wv][32 + lane];
        P[wv][lane] = sqrtf(vx * vx + vy * vy + vz * vz + 1e-12f);
    }
    __syncthreads();
    if (lane < 16) {
        float x = g_b1[lane];
        for (int mm = 0; mm < 16; ++mm) x += P[wv][mm] * g_w1[mm * 16 + lane];
        P[wv][16 + lane] = siluf(x);
    }
    __syncthreads();
    float sfin = 0.f;
    if (act && lane < 32) {
        float dl = g_b2[lane];
        for (int oo = 0; oo < 16; ++oo) dl += P[wv][16 + oo] * g_w2[oo * 32 + lane];
        sfin = sln + dl;
    }
    if (out) {
        if (act && lane < 32) out[(size_t)n * 80 + lane] = sfin;
        if (act && lane < 48) out[(size_t)n * 80 + 32 + o * 3 + c] = v3;
    } else {
        if (act && lane < 32) {
            sNew[n * 32 + lane] = sfin;
            s16New[n * 32 + lane] = bf16rn(sfin);
        }
        if (act && lane < 48) {
            vNew[n * 48 + lane] = v3;
            v16New[n * 48 + lane] = bf16rn(v3);
        }
    }
}

extern "C" void kernel_launch(void* const* d_in, const int* in_sizes, int n_in,
                              void* d_out, int out_size, void* d_ws, size_t ws_size,
                              hipStream_t stream) {
    auto F = [&](int i) { return (const float*)d_in[i]; };
    const int* z  = (const int*)d_in[31];
    const int* ei = (const int*)d_in[32];
    int N = in_sizes[0] / 3;
    int E = in_sizes[1];

    char* w = (char*)d_ws;
    size_t off = 0;
    auto take = [&](size_t bytes) { size_t cur = off; off += (bytes + 255) & ~(size_t)255; return cur; };
    float4* recA   = (float4*)(w + take((size_t)E * 16));
    float4* recQ4  = (float4*)(w + take((size_t)E * 16));
    float2* recQ2  = (float2*)(w + take((size_t)E * 8));
    int*   col_dst = (int*)(w + take((size_t)E * 4));
    int2*  rec_src = (int2*)(w + take((size_t)E * 8));
    float* tab     = (float*)(w + take((size_t)TTAB * 40 * 4));
    int* cnt_dst   = (int*)(w + take((size_t)2 * N * 4));
    int* cnt_src   = cnt_dst + N;
    int* row_dst   = (int*)(w + take((size_t)(N + 1) * 4));
    int* row_src   = (int*)(w + take((size_t)(N + 1) * 4));
    int* cur_dst   = (int*)(w + take((size_t)N * 4));
    int* cur_src   = (int*)(w + take((size_t)N * 4));
    float* sA      = (float*)(w + take((size_t)N * 32 * 4));
    float* vA      = (float*)(w + take((size_t)N * 48 * 4));
    float* sB      = (float*)(w + take((size_t)N * 32 * 4));
    float* vB      = (float*)(w + take((size_t)N * 48 * 4));
    unsigned short* s16A = (unsigned short*)(w + take((size_t)N * 32 * 2));
    unsigned short* v16A = (unsigned short*)(w + take((size_t)N * 48 * 2));
    unsigned short* s16B = (unsigned short*)(w + take((size_t)N * 32 * 2));
    unsigned short* v16B = (unsigned short*)(w + take((size_t)N * 48 * 2));

    hipMemsetAsync(cnt_dst, 0, (size_t)2 * N * 4, stream);

    k_table<<<TTAB, 256, 0, stream>>>(F(8), F(9), F(10), F(11),
                                      F(12), F(13), F(4), F(5), tab);
    k_count<<<(E + 255) / 256, 256, 0, stream>>>(ei, cnt_dst, cnt_src, E);
    k_scan2<<<2, 1024, 0, stream>>>(cnt_dst, row_dst, cur_dst,
                                    cnt_src, row_src, cur_src, N);
    k_edge_fill<<<(E + 255) / 256, 256, 0, stream>>>(F(0), F(1), ei, tab, z,
                                                     cur_dst, cur_src,
                                                     recA, recQ4, recQ2, col_dst,
                                                     rec_src, E);

    int nb = (N + 3) / 4;
    k_aggr<<<nb, 256, 0, stream>>>(row_src, rec_src, z, tab, F(3), F(2),
                                   F(6), F(7), sA, vA, s16A, v16A, N);

    float* sIn = sA; float* vIn = vA; unsigned short* s16In = s16A; unsigned short* v16In = v16A;
    float* sOut = sB; float* vOut = vB; unsigned short* s16Out = s16B; unsigned short* v16Out = v16B;
    for (int li = 0; li < 4; ++li) {
        float* outp = (li == 3) ? (float*)d_out : nullptr;
        k_layer<<<nb, 256, 0, stream>>>(row_dst, recA, recQ4, recQ2, col_dst,
                                        s16In, v16In, sIn, vIn,
                                        F(14) + li * 32 * 32, F(15) + li * 16 * 32,
                                        F(16) + li * 32 * 16, F(17) + li * 16 * 16,
                                        F(18) + li * 16 * 16,
                                        F(19) + li * 32 * 32, F(20) + li * 16 * 16,
                                        F(21) + li * 32 * 48, F(22) + li * 16 * 16,
                                        F(23) + li * 32 * 32, F(24) + li * 16 * 16,
                                        F(25) + li * 32, F(26) + li * 32,
                                        F(27) + li * 16 * 16, F(28) + li * 16,
                                        F(29) + li * 16 * 32, F(30) + li * 32,
                                        sOut, vOut, s16Out, v16Out, outp, N);
        float* ts = sIn; sIn = sOut; sOut = ts;
        float* tv = vIn; vIn = vOut; vOut = tv;
        unsigned short* t16 = s16In; s16In = s16Out; s16Out = t16;
        unsigned short* tv16 = v16In; v16In = v16Out; v16Out = tv16;
    }
}